// Round 11
// baseline (155.705 us; speedup 1.0000x reference)
//
#include <hip/hip_runtime.h>
#include <math.h>

#define N_NODES 50000
#define N_EDGES 800000
#define IN_DIM 128
#define OUT_DIM 16
#define N_HEADS 4
#define HID 64            // N_HEADS*OUT_DIM
#define AW_COLS 33        // 2*OUT_DIM+1
#define GN 16             // nodes per tile; 3125*16 = 50000 exact
#define GEMM_BLK ((N_NODES + GN - 1) / GN)             // 3125 tiles, x2 halves
#define HE 16             // edges per thread (hist)
#define HBLK ((N_EDGES + 256 * HE - 1) / (256 * HE))   // 196
#define MAXDEG 64         // padded bucket width; deg~Poisson(16), max~35 (12 sigma margin)

// LDS plan (R31): phase1 sWh 16KB @0 + sN 8KB @16384 = 24576 B.
// phase2 overlay: scr = 4 waves x 64 lanes x 9 dbl = 18432 B @0,
// h_lds = 16*32*4 = 2048 B @18432 -> 20480 <= 24576.
// 24576 B/block -> 6 blocks/CU (147456 <= 163840), 24 waves/CU.
#define SMEM_DOUBLES 3072                  // 24576 B
#define SCR_OFF_D 2304                     // h_lds at byte 18432

// R31: OUTPUT-SPLIT blocks. gemm is latency-bound at the 4-block/CU LDS cap
// (sW 32KB dominates); all pipes idle >=64%. Earlier claim that splitting
// outputs breaks the z-epilogue was WRONG on re-derivation: head hd's z needs
// only h[n][hd*16..+16), and heads {0,1} / {2,3} live entirely in output
// halves [0,32) / [32,64) -- 16-lane shuffle chains never cross the boundary.
// Each block does one 32-out half of a 16-node tile (hhalf=bid&1; pair shares
// the tile). sW half=16KB -> LDS 24576 -> 6 blocks/CU (+50% waves) at LESS
// LDS traffic per block. acc[2][4] (16 VGPR, ~40 total; (256,4) cap 128 --
// no R26-style spill possible). Reduction sum order per output VERBATIM R28
// -> h bit-identical; z chains same 16-lane trees -> z bit-identical.
// Cost: nodes staged twice (+25MB fetch ~ +4us, L3-resident second read).
// R30/R28 anchor: 155.1us; gemm 60-66, VALU ~35%, Occ ~33%.
// R29: f64 MFMA lane-mapping wrong (absmax 4.69) -- PERMANENTLY SHELVED.
// R27: W-from-global loses (line-divergent wq -> 16 L1 txns/load).
// R26: launch_bounds waves-arg beyond VGPR need -> spill catastrophe.
// R24: more waves without less traffic regresses.
// f64 GEMM LOCKED (near-one-hot softmax, argmax flips vs f32 ref).
__global__ __launch_bounds__(256, 4) void gemm_hist(
    const float* __restrict__ nodes, const float* __restrict__ W,
    const float* __restrict__ b, const float* __restrict__ attn_W,
    const float* __restrict__ attn_b, const float* __restrict__ edges,
    float* __restrict__ h, double* __restrict__ z_src, double* __restrict__ z_dst,
    const int* __restrict__ senders, const int* __restrict__ receivers,
    int* __restrict__ counts, int* __restrict__ srt_padded,
    double* __restrict__ Ssum) {
    __shared__ double smem_d[SMEM_DOUBLES];    // 24576 B, multi-phase overlay
    float* sWh = (float*)smem_d;               // 16 KB: 32 W rows, rotated
    float* sN = (float*)(smem_d + 2048);       // 8 KB @byte 16384, rotated
    int t = threadIdx.x;

    if (blockIdx.x < HBLK) {
        // ---------------- hist + direct bucket-scatter (R17) ----------------
        double* red = smem_d;
        int base = blockIdx.x * 256 * HE + t;
        double sp = 0.0;
        #pragma unroll
        for (int j = 0; j < HE; ++j) {
            int e = base + j * 256;
            if (e < N_EDGES) {
                int r = receivers[e];
                int rank = atomicAdd(&counts[r], 1);            // 0..deg-1
                if (rank < MAXDEG)
                    srt_padded[r * MAXDEG + rank] = senders[e];
                sp += (double)edges[senders[e]];
            }
        }
        red[t] = sp;
        __syncthreads();
        for (int off = 128; off > 0; off >>= 1) {
            if (t < off) red[t] += red[t + off];
            __syncthreads();
        }
        if (t == 0) atomicAdd(Ssum, red[0]);
    } else {
        // ---- gemm: one 32-out half of a 16-node tile; 4-way k-split ----
        int bidp = blockIdx.x - HBLK;          // [0, 6250)
        int hhalf = bidp & 1;                  // output half: 0 -> outs[0,32), 1 -> [32,64)
        int node0 = (bidp >> 1) * GN;

        for (int i4 = t; i4 < 32 * IN_DIM / 4; i4 += 256) {    // 1024 quads
            int o = i4 >> 5, kq = i4 & 31;     // o = local out row [0,32)
            float4 v = ((const float4*)W)[(hhalf * 32 + o) * (IN_DIM / 4) + kq];
            *(float4*)&sWh[o * IN_DIM + (((kq + o) & 31) << 2)] = v;
        }
        for (int i4 = t; i4 < GN * IN_DIM / 4; i4 += 256) {    // 512 quads, rotated
            int ln = i4 >> 5, kq = i4 & 31;
            float4 v = ((const float4*)nodes)[(long long)(node0 + ln) * (IN_DIM / 4) + kq];
            *(float4*)&sN[ln * IN_DIM + (((kq + ln) & 31) << 2)] = v;
        }
        __syncthreads();                   // barrier 1

        int w = t >> 6, l = t & 63;
        int og = l & 15;                   // local outs og + 16j, j=0..1
        int ng = l >> 4;                   // nodes   ng + 4i,  i=0..3
        int kbase = w * 8;                 // this wave's kq range [kbase, kbase+8)

        double acc[2][4];                  // [j][i]
        #pragma unroll
        for (int j = 0; j < 2; ++j)
            #pragma unroll
            for (int i = 0; i < 4; ++i) acc[j][i] = 0.0;

        #pragma unroll
        for (int s = 0; s < 8; ++s) {
            int kq = kbase + s;
            float4 wq[2], xq[4];
            #pragma unroll
            for (int j = 0; j < 2; ++j) {
                int o = og + 16 * j;
                wq[j] = *(const float4*)&sWh[o * IN_DIM + (((kq + o) & 31) << 2)];
            }
            #pragma unroll
            for (int i = 0; i < 4; ++i) {
                int n = ng + 4 * i;
                xq[i] = *(const float4*)&sN[n * IN_DIM + (((kq + n) & 31) << 2)];
            }
            #pragma unroll
            for (int j = 0; j < 2; ++j) {
                double wx = (double)wq[j].x, wy = (double)wq[j].y;
                double wz = (double)wq[j].z, ww = (double)wq[j].w;
                #pragma unroll
                for (int i = 0; i < 4; ++i) {
                    double nx = (double)xq[i].x, ny = (double)xq[i].y;
                    double nz = (double)xq[i].z, nw = (double)xq[i].w;
                    acc[j][i] += wx * nx; acc[j][i] += wy * ny;
                    acc[j][i] += wz * nz; acc[j][i] += ww * nw;
                }
            }
        }
        __syncthreads();                   // barrier 2: sWh/sN reads done

        // ---- k-reduction: all waves dump; waves 0,1 sum quad j=w ----
        double* scr = smem_d;              // overlays dead staging; 18432 B
        float* h_lds = (float*)(smem_d + SCR_OFF_D);   // 2 KB @byte 18432
        {
            double* dst = &scr[(w * 64 + l) * 9];
            #pragma unroll
            for (int j = 0; j < 2; ++j)
                #pragma unroll
                for (int i = 0; i < 4; ++i) dst[j * 4 + i] = acc[j][i];
        }
        __syncthreads();                   // barrier 3
        if (w < 2) {
            int jw = w;                    // finalize local outs og + 16w
            double bj = (double)b[hhalf * 32 + og + 16 * jw];
            #pragma unroll
            for (int i = 0; i < 4; ++i) {
                double sum = bj;
                sum += scr[(0 * 64 + l) * 9 + jw * 4 + i];   // k[0,8)
                sum += scr[(1 * 64 + l) * 9 + jw * 4 + i];   // k[8,16)
                sum += scr[(2 * 64 + l) * 9 + jw * 4 + i];   // k[16,24)
                sum += scr[(3 * 64 + l) * 9 + jw * 4 + i];   // k[24,32)
                h_lds[(ng + 4 * i) * 32 + og + 16 * jw] = (float)sum;
            }
        }
        __syncthreads();                   // barrier 4

        // ---- epilogue: heads {hhalf*2, hhalf*2+1}; chains verbatim R28 ----
        int half = l >> 5;
        int o2 = l & 31;                   // local out column [0,32)
        int nwbase = w * 4 + half * 2;
        int hdl = o2 >> 4, d = o2 & 15;
        int hdg = hhalf * 2 + hdl;         // global head
        double aw0 = (double)attn_W[hdg * AW_COLS + d];            // a_src
        double aw1 = (double)attn_W[hdg * AW_COLS + OUT_DIM + d];  // a_dst
        double wE = (double)attn_W[hdg * AW_COLS + 2 * OUT_DIM];
        double bbv = (double)attn_b[hdg];
        #pragma unroll
        for (int j = 0; j < 2; ++j) {
            int nl = nwbase + j;
            int n = node0 + nl;            // always < 50000 (exact tiling)
            float hf = h_lds[nl * 32 + o2];
            double c0 = (double)hf * aw0;
            double c1 = (double)hf * aw1;
            #pragma unroll
            for (int k = 1; k <= 8; k <<= 1) {
                c0 += __shfl_xor(c0, k, 64);
                c1 += __shfl_xor(c1, k, 64);
            }
            if (d == 0) {
                double se = (double)edges[n];
                z_src[n * N_HEADS + hdg] = c0 + se * wE;
                z_dst[n * N_HEADS + hdg] = c1 + bbv;
            }
        }
        // h write: this block's half-columns for 16 nodes (128 float4)
        if (t < 128) {
            int node = t >> 3, c = t & 7;
            ((float4*)h)[(long long)(node0 + node) * (HID / 4) + hhalf * 8 + c] =
                ((const float4*)h_lds)[node * 8 + c];
        }
    }
}

// R22 form (best known, FROZEN). TWO nodes per wave, phases pairwise
// interleaved; near-one-hot softmax -> ballot loop does ~1-4 gathers/node
// (R23's dense rewrite did 16x traffic, +12us -- don't retry).
__global__ __launch_bounds__(256, 8) void node_fused(
    const float* __restrict__ h, const double* __restrict__ z_src,
    const double* __restrict__ z_dst,
    const int* __restrict__ srt_padded, const int* __restrict__ counts,
    const double* __restrict__ Ssum, float* __restrict__ out) {
    int w = threadIdx.x >> 6;
    int lane = threadIdx.x & 63;
    int nA = blockIdx.x * 8 + w * 2;     // grid exact: 6250*8 = 50000
    int nB = nA + 1;
    int hd = lane >> 4, q = lane & 15;

    int degA = counts[nA]; if (degA > MAXDEG) degA = MAXDEG;
    int degB = counts[nB]; if (degB > MAXDEG) degB = MAXDEG;
    double S = 4.0 * Ssum[0];                       // sent_e tiled over heads
    double zdA = z_dst[nA * N_HEADS + hd];
    double zdB = z_dst[nB * N_HEADS + hd];

    // ---- edge-id gather (both nodes issued before use) ----
    int sA[4], sB[4];
    #pragma unroll
    for (int j = 0; j < 4; ++j) {
        int ei = q + 16 * j;
        sA[j] = (ei < degA) ? srt_padded[nA * MAXDEG + ei] : 0;
        sB[j] = (ei < degB) ? srt_padded[nB * MAXDEG + ei] : 0;
    }
    // ---- z_src scatter-gather + leaky (f64, then round) — bit-exact ----
    float yA[4], yB[4];
    #pragma unroll
    for (int j = 0; j < 4; ++j) {
        int ei = q + 16 * j;
        yA[j] = -INFINITY;
        yB[j] = -INFINITY;
        if (ei < degA) {
            double yy = z_src[sA[j] * N_HEADS + hd] + zdA;
            yy = yy > 0.0 ? yy : 0.01 * yy;
            yA[j] = (float)yy;
        }
        if (ei < degB) {
            double yy = z_src[sB[j] * N_HEADS + hd] + zdB;
            yy = yy > 0.0 ? yy : 0.01 * yy;
            yB[j] = (float)yy;
        }
    }
    // ---- per-head max: two butterfly chains interleaved ----
    float mA = fmaxf(fmaxf(yA[0], yA[1]), fmaxf(yA[2], yA[3]));
    float mB = fmaxf(fmaxf(yB[0], yB[1]), fmaxf(yB[2], yB[3]));
    #pragma unroll
    for (int k = 1; k <= 8; k <<= 1) {
        mA = fmaxf(mA, __shfl_xor(mA, k, 64));
        mB = fmaxf(mB, __shfl_xor(mB, k, 64));
    }
    // ---- exp + denominator (same expression order as R21) ----
    float evA[4], evB[4];
    float dA = 0.f, dB = 0.f;
    #pragma unroll
    for (int j = 0; j < 4; ++j) {
        evA[j] = (yA[j] == -INFINITY) ? 0.f
               : __expf((float)(S * ((double)yA[j] - (double)mA)));
        dA += evA[j];
        evB[j] = (yB[j] == -INFINITY) ? 0.f
               : __expf((float)(S * ((double)yB[j] - (double)mB)));
        dB += evB[j];
    }
    #pragma unroll
    for (int k = 1; k <= 8; k <<= 1) {
        dA += __shfl_xor(dA, k, 64);
        dB += __shfl_xor(dB, k, 64);
    }
    // ---- ballot-compressed accumulate, node A then node B (order preserved) ----
    float accA = 0.f;
    #pragma unroll
    for (int j = 0; j < 4; ++j) {
        unsigned long long mk = __ballot(evA[j] != 0.f);
        unsigned um = (unsigned)((mk | (mk >> 16) | (mk >> 32) | (mk >> 48)) & 0xFFFFull);
        while (um) {
            int qq = __builtin_ctz(um);
            um &= um - 1;
            int src = (lane & 48) | qq;                 // own head's copy
            float evv = __shfl(evA[j], src, 64);
            int sj = __shfl(sA[j], src, 64);
            if (evv != 0.f)
                accA = fmaf(evv, h[sj * HID + lane], accA);
        }
    }
    float accB = 0.f;
    #pragma unroll
    for (int j = 0; j < 4; ++j) {
        unsigned long long mk = __ballot(evB[j] != 0.f);
        unsigned um = (unsigned)((mk | (mk >> 16) | (mk >> 32) | (mk >> 48)) & 0xFFFFull);
        while (um) {
            int qq = __builtin_ctz(um);
            um &= um - 1;
            int src = (lane & 48) | qq;
            float evv = __shfl(evB[j], src, 64);
            int sj = __shfl(sB[j], src, 64);
            if (evv != 0.f)
                accB = fmaf(evv, h[sj * HID + lane], accB);
        }
    }
    float rA = (dA > 0.f) ? accA / dA : 0.f;
    float rB = (dB > 0.f) ? accB / dB : 0.f;
    out[nA * HID + lane] = rA > 0.f ? rA : 0.01f * rA;
    out[nB * HID + lane] = rB > 0.f ? rB : 0.01f * rB;
}

static inline char* ws_take(char*& p, size_t bytes) {
    char* cur = p;
    p += (bytes + 255) & ~(size_t)255;   // keep every buffer 256B-aligned
    return cur;
}

extern "C" void kernel_launch(void* const* d_in, const int* in_sizes, int n_in,
                              void* d_out, int out_size, void* d_ws, size_t ws_size,
                              hipStream_t stream) {
    const float* nodes     = (const float*)d_in[0];
    const float* edges     = (const float*)d_in[1];
    const int*   senders   = (const int*)d_in[2];
    const int*   receivers = (const int*)d_in[3];
    const float* W         = (const float*)d_in[4];
    const float* b         = (const float*)d_in[5];
    const float* attn_W    = (const float*)d_in[6];
    const float* attn_b    = (const float*)d_in[7];
    float* out = (float*)d_out;

    char* p = (char*)d_ws;
    float*  h          = (float*)ws_take(p, sizeof(float) * N_NODES * HID);
    double* z_src      = (double*)ws_take(p, sizeof(double) * N_NODES * N_HEADS);
    double* z_dst      = (double*)ws_take(p, sizeof(double) * N_NODES * N_HEADS);
    int*    counts     = (int*)ws_take(p, sizeof(int) * N_NODES);   // contiguous with
    char*   zpad       = ws_take(p, 256);                           // Ssum: one memset
    double* Ssum       = (double*)zpad;
    int*    srt_padded = (int*)ws_take(p, sizeof(int) * (size_t)N_NODES * MAXDEG);

    // counts (256B-rounded) + the Ssum pad in one memset; srt_padded needs no init
    hipMemsetAsync(counts, 0, ((sizeof(int) * N_NODES + 255) & ~(size_t)255) + 256, stream);

    gemm_hist<<<HBLK + 2 * GEMM_BLK, 256, 0, stream>>>(
        nodes, W, b, attn_W, attn_b, edges, h, z_src, z_dst,
        senders, receivers, counts, srt_padded, Ssum);
    node_fused<<<(N_NODES + 7) / 8, 256, 0, stream>>>(
        h, z_src, z_dst, srt_padded, counts, Ssum, out);
}

// Round 12
// 153.469 us; speedup vs baseline: 1.0146x; 1.0146x over previous
//
#include <hip/hip_runtime.h>
#include <math.h>

#define N_NODES 50000
#define N_EDGES 800000
#define IN_DIM 128
#define OUT_DIM 16
#define N_HEADS 4
#define HID 64            // N_HEADS*OUT_DIM
#define AW_COLS 33        // 2*OUT_DIM+1
#define GN 16             // nodes per tile; 3125*16 = 50000 exact
#define GEMM_BLK ((N_NODES + GN - 1) / GN)             // 3125 tiles, x2 halves
#define HE 16             // edges per thread (hist)
#define HBLK ((N_EDGES + 256 * HE - 1) / (256 * HE))   // 196
#define MAXDEG 64         // padded bucket width; deg~Poisson(16), max~35 (12 sigma margin)

// LDS plan (R33 = R31 sizes): phase1 sWh 16KB @0 + sN 8KB @16384 = 24576 B.
// phase2 overlay (f32 now): scr = 4 waves x 64 lanes x 9 f32 = 9216 B @0,
// h_lds = 16*32*4 = 2048 B @9216 -> 11264 <= 24576.
// 24576 B/block -> 6 blocks/CU, 24 waves/CU.
#define SMEM_DOUBLES 3072                  // 24576 B
#define SCR_OFF_F 2304                     // floats; h_lds at byte 9216

// R33 = R31 + ONE variable: GEMM in f32. Rationale: 6 structures (R21-R31)
// all land 62-67us; occupancy 33->54% and traffic cuts moved NOTHING; VALU
// busy (~29us) converged on the f64 arithmetic itself. Total tracks
// gemm_max 1:1 (+90-95us constant = node_fused + harness resets), so gemm
// duration is the only live lever, and dtype is the only untried axis.
// LOCK RE-EXAMINED: the f64 kernel computes the TRUE argmax and PASSES vs the
// f32 jax ref -> top-1 logit margins exceed the ref's own f32 noise (~1e-7
// rel). f32-accumulated h adds same-order noise -> same margins protect it.
// Duplicate-edge bitwise ties stay ties (identical inputs -> identical y).
// z-path CODE UNCHANGED (f64 chains from f32 h); node_fused/hist frozen.
// REVERT PATH: R31 (155.7us, absmax 0.015625) if absmax > 0.09375.
// R29: f64 MFMA lane-mapping wrong -- PERMANENTLY SHELVED.
// R27: W-from-global loses (line-divergent wq). R26: launch_bounds spill.
// R24: more waves without less traffic regresses.
__global__ __launch_bounds__(256, 4) void gemm_hist(
    const float* __restrict__ nodes, const float* __restrict__ W,
    const float* __restrict__ b, const float* __restrict__ attn_W,
    const float* __restrict__ attn_b, const float* __restrict__ edges,
    float* __restrict__ h, double* __restrict__ z_src, double* __restrict__ z_dst,
    const int* __restrict__ senders, const int* __restrict__ receivers,
    int* __restrict__ counts, int* __restrict__ srt_padded,
    double* __restrict__ Ssum) {
    __shared__ double smem_d[SMEM_DOUBLES];    // 24576 B, multi-phase overlay
    float* sWh = (float*)smem_d;               // 16 KB: 32 W rows, rotated
    float* sN = (float*)(smem_d + 2048);       // 8 KB @byte 16384, rotated
    int t = threadIdx.x;

    if (blockIdx.x < HBLK) {
        // ---------------- hist + direct bucket-scatter (R17) ----------------
        double* red = smem_d;
        int base = blockIdx.x * 256 * HE + t;
        double sp = 0.0;
        #pragma unroll
        for (int j = 0; j < HE; ++j) {
            int e = base + j * 256;
            if (e < N_EDGES) {
                int r = receivers[e];
                int rank = atomicAdd(&counts[r], 1);            // 0..deg-1
                if (rank < MAXDEG)
                    srt_padded[r * MAXDEG + rank] = senders[e];
                sp += (double)edges[senders[e]];
            }
        }
        red[t] = sp;
        __syncthreads();
        for (int off = 128; off > 0; off >>= 1) {
            if (t < off) red[t] += red[t + off];
            __syncthreads();
        }
        if (t == 0) atomicAdd(Ssum, red[0]);
    } else {
        // ---- gemm: one 32-out half of a 16-node tile; 4-way k-split; f32 ----
        int bidp = blockIdx.x - HBLK;          // [0, 6250)
        int hhalf = bidp & 1;                  // output half: 0 -> outs[0,32), 1 -> [32,64)
        int node0 = (bidp >> 1) * GN;

        for (int i4 = t; i4 < 32 * IN_DIM / 4; i4 += 256) {    // 1024 quads
            int o = i4 >> 5, kq = i4 & 31;     // o = local out row [0,32)
            float4 v = ((const float4*)W)[(hhalf * 32 + o) * (IN_DIM / 4) + kq];
            *(float4*)&sWh[o * IN_DIM + (((kq + o) & 31) << 2)] = v;
        }
        for (int i4 = t; i4 < GN * IN_DIM / 4; i4 += 256) {    // 512 quads, rotated
            int ln = i4 >> 5, kq = i4 & 31;
            float4 v = ((const float4*)nodes)[(long long)(node0 + ln) * (IN_DIM / 4) + kq];
            *(float4*)&sN[ln * IN_DIM + (((kq + ln) & 31) << 2)] = v;
        }
        __syncthreads();                   // barrier 1

        int w = t >> 6, l = t & 63;
        int og = l & 15;                   // local outs og + 16j, j=0..1
        int ng = l >> 4;                   // nodes   ng + 4i,  i=0..3
        int kbase = w * 8;                 // this wave's kq range [kbase, kbase+8)

        float acc[2][4];                   // [j][i] -- f32 accumulate (R33)
        #pragma unroll
        for (int j = 0; j < 2; ++j)
            #pragma unroll
            for (int i = 0; i < 4; ++i) acc[j][i] = 0.f;

        #pragma unroll
        for (int s = 0; s < 8; ++s) {
            int kq = kbase + s;
            float4 wq[2], xq[4];
            #pragma unroll
            for (int j = 0; j < 2; ++j) {
                int o = og + 16 * j;
                wq[j] = *(const float4*)&sWh[o * IN_DIM + (((kq + o) & 31) << 2)];
            }
            #pragma unroll
            for (int i = 0; i < 4; ++i) {
                int n = ng + 4 * i;
                xq[i] = *(const float4*)&sN[n * IN_DIM + (((kq + n) & 31) << 2)];
            }
            #pragma unroll
            for (int j = 0; j < 2; ++j) {
                #pragma unroll
                for (int i = 0; i < 4; ++i) {
                    acc[j][i] = fmaf(wq[j].x, xq[i].x, acc[j][i]);
                    acc[j][i] = fmaf(wq[j].y, xq[i].y, acc[j][i]);
                    acc[j][i] = fmaf(wq[j].z, xq[i].z, acc[j][i]);
                    acc[j][i] = fmaf(wq[j].w, xq[i].w, acc[j][i]);
                }
            }
        }
        __syncthreads();                   // barrier 2: sWh/sN reads done

        // ---- k-reduction (f32): all waves dump; waves 0,1 sum quad j=w ----
        float* scrF = (float*)smem_d;      // overlays dead staging; 9216 B
        float* h_lds = (float*)smem_d + SCR_OFF_F;     // 2 KB @byte 9216
        {
            float* dst = &scrF[(w * 64 + l) * 9];
            #pragma unroll
            for (int j = 0; j < 2; ++j)
                #pragma unroll
                for (int i = 0; i < 4; ++i) dst[j * 4 + i] = acc[j][i];
        }
        __syncthreads();                   // barrier 3
        if (w < 2) {
            int jw = w;                    // finalize local outs og + 16w
            #pragma unroll
            for (int i = 0; i < 4; ++i) {
                float sum = b[hhalf * 32 + og + 16 * jw];
                sum += scrF[(0 * 64 + l) * 9 + jw * 4 + i];   // k[0,32)
                sum += scrF[(1 * 64 + l) * 9 + jw * 4 + i];   // k[32,64)
                sum += scrF[(2 * 64 + l) * 9 + jw * 4 + i];   // k[64,96)
                sum += scrF[(3 * 64 + l) * 9 + jw * 4 + i];   // k[96,128)
                h_lds[(ng + 4 * i) * 32 + og + 16 * jw] = sum;
            }
        }
        __syncthreads();                   // barrier 4

        // ---- epilogue: heads {hhalf*2, hhalf*2+1}; f64 chains verbatim R31 ----
        int half = l >> 5;
        int o2 = l & 31;                   // local out column [0,32)
        int nwbase = w * 4 + half * 2;
        int hdl = o2 >> 4, d = o2 & 15;
        int hdg = hhalf * 2 + hdl;         // global head
        double aw0 = (double)attn_W[hdg * AW_COLS + d];            // a_src
        double aw1 = (double)attn_W[hdg * AW_COLS + OUT_DIM + d];  // a_dst
        double wE = (double)attn_W[hdg * AW_COLS + 2 * OUT_DIM];
        double bbv = (double)attn_b[hdg];
        #pragma unroll
        for (int j = 0; j < 2; ++j) {
            int nl = nwbase + j;
            int n = node0 + nl;            // always < 50000 (exact tiling)
            float hf = h_lds[nl * 32 + o2];
            double c0 = (double)hf * aw0;
            double c1 = (double)hf * aw1;
            #pragma unroll
            for (int k = 1; k <= 8; k <<= 1) {
                c0 += __shfl_xor(c0, k, 64);
                c1 += __shfl_xor(c1, k, 64);
            }
            if (d == 0) {
                double se = (double)edges[n];
                z_src[n * N_HEADS + hdg] = c0 + se * wE;
                z_dst[n * N_HEADS + hdg] = c1 + bbv;
            }
        }
        // h write: this block's half-columns for 16 nodes (128 float4)
        if (t < 128) {
            int node = t >> 3, c = t & 7;
            ((float4*)h)[(long long)(node0 + node) * (HID / 4) + hhalf * 8 + c] =
                ((const float4*)h_lds)[node * 8 + c];
        }
    }
}

// R22 form (best known, FROZEN). TWO nodes per wave, phases pairwise
// interleaved; near-one-hot softmax -> ballot loop does ~1-4 gathers/node
// (R23's dense rewrite did 16x traffic, +12us -- don't retry).
__global__ __launch_bounds__(256, 8) void node_fused(
    const float* __restrict__ h, const double* __restrict__ z_src,
    const double* __restrict__ z_dst,
    const int* __restrict__ srt_padded, const int* __restrict__ counts,
    const double* __restrict__ Ssum, float* __restrict__ out) {
    int w = threadIdx.x >> 6;
    int lane = threadIdx.x & 63;
    int nA = blockIdx.x * 8 + w * 2;     // grid exact: 6250*8 = 50000
    int nB = nA + 1;
    int hd = lane >> 4, q = lane & 15;

    int degA = counts[nA]; if (degA > MAXDEG) degA = MAXDEG;
    int degB = counts[nB]; if (degB > MAXDEG) degB = MAXDEG;
    double S = 4.0 * Ssum[0];                       // sent_e tiled over heads
    double zdA = z_dst[nA * N_HEADS + hd];
    double zdB = z_dst[nB * N_HEADS + hd];

    // ---- edge-id gather (both nodes issued before use) ----
    int sA[4], sB[4];
    #pragma unroll
    for (int j = 0; j < 4; ++j) {
        int ei = q + 16 * j;
        sA[j] = (ei < degA) ? srt_padded[nA * MAXDEG + ei] : 0;
        sB[j] = (ei < degB) ? srt_padded[nB * MAXDEG + ei] : 0;
    }
    // ---- z_src scatter-gather + leaky (f64, then round) ----
    float yA[4], yB[4];
    #pragma unroll
    for (int j = 0; j < 4; ++j) {
        int ei = q + 16 * j;
        yA[j] = -INFINITY;
        yB[j] = -INFINITY;
        if (ei < degA) {
            double yy = z_src[sA[j] * N_HEADS + hd] + zdA;
            yy = yy > 0.0 ? yy : 0.01 * yy;
            yA[j] = (float)yy;
        }
        if (ei < degB) {
            double yy = z_src[sB[j] * N_HEADS + hd] + zdB;
            yy = yy > 0.0 ? yy : 0.01 * yy;
            yB[j] = (float)yy;
        }
    }
    // ---- per-head max: two butterfly chains interleaved ----
    float mA = fmaxf(fmaxf(yA[0], yA[1]), fmaxf(yA[2], yA[3]));
    float mB = fmaxf(fmaxf(yB[0], yB[1]), fmaxf(yB[2], yB[3]));
    #pragma unroll
    for (int k = 1; k <= 8; k <<= 1) {
        mA = fmaxf(mA, __shfl_xor(mA, k, 64));
        mB = fmaxf(mB, __shfl_xor(mB, k, 64));
    }
    // ---- exp + denominator (same expression order as R21) ----
    float evA[4], evB[4];
    float dA = 0.f, dB = 0.f;
    #pragma unroll
    for (int j = 0; j < 4; ++j) {
        evA[j] = (yA[j] == -INFINITY) ? 0.f
               : __expf((float)(S * ((double)yA[j] - (double)mA)));
        dA += evA[j];
        evB[j] = (yB[j] == -INFINITY) ? 0.f
               : __expf((float)(S * ((double)yB[j] - (double)mB)));
        dB += evB[j];
    }
    #pragma unroll
    for (int k = 1; k <= 8; k <<= 1) {
        dA += __shfl_xor(dA, k, 64);
        dB += __shfl_xor(dB, k, 64);
    }
    // ---- ballot-compressed accumulate, node A then node B (order preserved) ----
    float accA = 0.f;
    #pragma unroll
    for (int j = 0; j < 4; ++j) {
        unsigned long long mk = __ballot(evA[j] != 0.f);
        unsigned um = (unsigned)((mk | (mk >> 16) | (mk >> 32) | (mk >> 48)) & 0xFFFFull);
        while (um) {
            int qq = __builtin_ctz(um);
            um &= um - 1;
            int src = (lane & 48) | qq;                 // own head's copy
            float evv = __shfl(evA[j], src, 64);
            int sj = __shfl(sA[j], src, 64);
            if (evv != 0.f)
                accA = fmaf(evv, h[sj * HID + lane], accA);
        }
    }
    float accB = 0.f;
    #pragma unroll
    for (int j = 0; j < 4; ++j) {
        unsigned long long mk = __ballot(evB[j] != 0.f);
        unsigned um = (unsigned)((mk | (mk >> 16) | (mk >> 32) | (mk >> 48)) & 0xFFFFull);
        while (um) {
            int qq = __builtin_ctz(um);
            um &= um - 1;
            int src = (lane & 48) | qq;
            float evv = __shfl(evB[j], src, 64);
            int sj = __shfl(sB[j], src, 64);
            if (evv != 0.f)
                accB = fmaf(evv, h[sj * HID + lane], accB);
        }
    }
    float rA = (dA > 0.f) ? accA / dA : 0.f;
    float rB = (dB > 0.f) ? accB / dB : 0.f;
    out[nA * HID + lane] = rA > 0.f ? rA : 0.01f * rA;
    out[nB * HID + lane] = rB > 0.f ? rB : 0.01f * rB;
}

static inline char* ws_take(char*& p, size_t bytes) {
    char* cur = p;
    p += (bytes + 255) & ~(size_t)255;   // keep every buffer 256B-aligned
    return cur;
}

extern "C" void kernel_launch(void* const* d_in, const int* in_sizes, int n_in,
                              void* d_out, int out_size, void* d_ws, size_t ws_size,
                              hipStream_t stream) {
    const float* nodes     = (const float*)d_in[0];
    const float* edges     = (const float*)d_in[1];
    const int*   senders   = (const int*)d_in[2];
    const int*   receivers = (const int*)d_in[3];
    const float* W         = (const float*)d_in[4];
    const float* b         = (const float*)d_in[5];
    const float* attn_W    = (const float*)d_in[6];
    const float* attn_b    = (const float*)d_in[7];
    float* out = (float*)d_out;

    char* p = (char*)d_ws;
    float*  h          = (float*)ws_take(p, sizeof(float) * N_NODES * HID);
    double* z_src      = (double*)ws_take(p, sizeof(double) * N_NODES * N_HEADS);
    double* z_dst      = (double*)ws_take(p, sizeof(double) * N_NODES * N_HEADS);
    int*    counts     = (int*)ws_take(p, sizeof(int) * N_NODES);   // contiguous with
    char*   zpad       = ws_take(p, 256);                           // Ssum: one memset
    double* Ssum       = (double*)zpad;
    int*    srt_padded = (int*)ws_take(p, sizeof(int) * (size_t)N_NODES * MAXDEG);

    // counts (256B-rounded) + the Ssum pad in one memset; srt_padded needs no init
    hipMemsetAsync(counts, 0, ((sizeof(int) * N_NODES + 255) & ~(size_t)255) + 256, stream);

    gemm_hist<<<HBLK + 2 * GEMM_BLK, 256, 0, stream>>>(
        nodes, W, b, attn_W, attn_b, edges, h, z_src, z_dst,
        senders, receivers, counts, srt_padded, Ssum);
    node_fused<<<(N_NODES + 7) / 8, 256, 0, stream>>>(
        h, z_src, z_dst, srt_padded, counts, Ssum, out);
}